// Round 1
// baseline (468.240 us; speedup 1.0000x reference)
//
#include <hip/hip_runtime.h>
#include <hip/hip_bf16.h>
#include <stdint.h>

#define BATCH 8192
#define DIM   2048
#define NEXP  8
#define BM    128
#define BN    128
#define BK    32
#define NITER (DIM / BK)   // 64
#define MAX_TILES 72
#define NBLK  (DIM / BN)   // 16
#define NPAD  1024
#define NCVT  16384        // (8*2048*2048 bf16 bytes)/16B/256thr

typedef __bf16 bf16x8 __attribute__((ext_vector_type(8)));
typedef float  f32x4  __attribute__((ext_vector_type(4)));

// ---- workspace layout ----
// counts@0(8) cursor@16(8) seg@32(8) ntiles@48 tileExp@64(96) tilePos0@160(96)
// tileVal@256(96) rowmap@512(9216)
// xg (bf16) @ byte 40960 ; Wb (bf16) @ byte 37,789,696
#define XG_BYTE_OFF 40960ull
#define WB_BYTE_OFF 37789696ull
#define WS_NEED     104898560ull

#define AS1(p) ((const __attribute__((address_space(1))) void*)(p))
#define AS3(p) ((__attribute__((address_space(3))) void*)(p))

__device__ __forceinline__ unsigned f2bf2(float lo, float hi) {
    unsigned ul = __float_as_uint(lo), uh = __float_as_uint(hi);
    ul = (ul + 0x7FFFu + ((ul >> 16) & 1u)) >> 16;   // RNE
    uh = (uh + 0x7FFFu + ((uh >> 16) & 1u)) >> 16;
    return (uh << 16) | ul;
}

// one dispatch: LDS histogram of ids + serial segment/tile plan
__global__ void k_plan(const int* __restrict__ ids, int* __restrict__ ws) {
    __shared__ int sc[NEXP];
    int t = threadIdx.x;
    if (t < NEXP) sc[t] = 0;
    __syncthreads();
    for (int i = t; i < BATCH; i += 256) atomicAdd(&sc[ids[i]], 1);
    __syncthreads();
    if (t == 0) {
        int pos = 0, mt = 0;
        for (int e = 0; e < NEXP; e++) {
            int c = sc[e];
            ws[e]      = c;
            ws[16 + e] = 0;
            ws[32 + e] = pos;
            int ntl = (c + BM - 1) / BM;
            for (int tt = 0; tt < ntl; tt++) {
                ws[64  + mt] = e;
                ws[160 + mt] = pos + tt * BM;
                int v = c - tt * BM;
                ws[256 + mt] = v < BM ? v : BM;
                mt++;
            }
            pos += ntl * BM;
        }
        ws[48] = mt;
    }
}

// merged preprocessing:
//   blocks [0, BATCH)             : gather+convert row b of x into xg (compacted)
//   blocks [BATCH, BATCH+NPAD)    : zero padding rows
//   blocks [BATCH+NPAD, +NCVT)    : W fp32 -> bf16 (32B in / 16B out per thread)
// gather blocks dispatch first so their atomic/latency phase overlaps the
// pure-streaming W conversion.
__global__ void k_prep(const float* __restrict__ x, const int* __restrict__ ids,
                       int* __restrict__ ws, unsigned short* __restrict__ xg,
                       int* __restrict__ rowmap,
                       const float4* __restrict__ W, uint4* __restrict__ Wb) {
    int b = blockIdx.x;
    if (b >= BATCH + NPAD) {
        // ---- W conversion ----
        size_t o = (size_t)(b - (BATCH + NPAD)) * 256 + threadIdx.x; // uint4 idx
        float4 a = W[o * 2], c = W[o * 2 + 1];
        uint4 v;
        v.x = f2bf2(a.x, a.y);  v.y = f2bf2(a.z, a.w);
        v.z = f2bf2(c.x, c.y);  v.w = f2bf2(c.z, c.w);
        Wb[o] = v;
        return;
    }
    if (b >= BATCH) {
        // ---- zero padding rows ----
        int p = b - BATCH;
        int row = -1;
        for (int e = 0; e < NEXP; e++) {
            int c = ws[e];
            int pe = ((c + BM - 1) & ~(BM - 1)) - c;
            if (p < pe) { row = ws[32 + e] + c + p; break; }
            p -= pe;
        }
        if (row < 0) return;
        uint4* o = (uint4*)(xg + (size_t)row * DIM);
        uint4 z = make_uint4(0, 0, 0, 0);
        for (int t = threadIdx.x; t < DIM / 8; t += 256) o[t] = z;
        return;
    }
    // ---- gather row b ----
    __shared__ int spos;
    if (threadIdx.x == 0) {
        int e = ids[b];
        int p = ws[32 + e] + atomicAdd(&ws[16 + e], 1);
        spos = p;
        rowmap[p] = b;
    }
    __syncthreads();
    int pos = spos;
    const float4* xr = (const float4*)(x + (size_t)b * DIM);
    uint4* o = (uint4*)(xg + (size_t)pos * DIM);
    int t = threadIdx.x;                      // DIM/8 == 256: one chunk/thread
    float4 a = xr[t * 2], b4 = xr[t * 2 + 1];
    uint4 v;
    v.x = f2bf2(a.x, a.y);   v.y = f2bf2(a.z, a.w);
    v.z = f2bf2(b4.x, b4.y); v.w = f2bf2(b4.z, b4.w);
    o[t] = v;
}

// grouped GEMM: 128x128 tile, 4 waves (2x2 of 64x64), BK=32.
// TRIPLE-BUFFERED LDS, 2-deep prefetch, counted vmcnt (T3+T4):
//   per iter: s_waitcnt vmcnt(4)  (loads(i) done, loads(i+1) stay in flight)
//             s_barrier; ISSUE(i+2); ds_read(i); MFMA(i)
// Safety: barrier(i) proves all waves consumed buf[(i-1)%3] (ds_read data is
// in regs before MFMA issue), so ISSUE(i+2) overwriting it is race-free.
// Swizzle: 16B chunk at LDS position p of row r holds logical chunk
// p ^ ((r>>1)&3) -> 2-way (free) bank aliasing on ds_read_b128 phases,
// applied on the STAGING SOURCE address (dest stays wave-uniform contiguous).
// XCD swizzle: all 16 n-blocks of an m-tile land on one XCD (A-panel L2
// locality); m-tiles round-robin across XCDs (balanced for any ntiles).
__launch_bounds__(256)
__global__ void k_gemm(const unsigned short* __restrict__ xg,
                       const unsigned short* __restrict__ Wb,
                       const float* __restrict__ bias,
                       const int* __restrict__ ws, const int* __restrict__ rowmap,
                       float* __restrict__ out) {
    int bid = blockIdx.x;                 // 0..1151
    int g = bid >> 3, r = bid & 7;        // XCD = bid % 8
    int nb = g & 15;                      // n-block within m-tile
    int mt = ((g >> 4) << 3) + r;         // m-tile, round-robin across XCDs
    if (mt >= ws[48]) return;
    int e     = ws[64  + mt];
    int pos0  = ws[160 + mt];
    int valid = ws[256 + mt];
    int n0 = nb * BN;

    __shared__ unsigned short lds[3][8192];  // [buf][0..4095]=A, [4096..8191]=B; 48 KB

    int tid = threadIdx.x;
    int w = tid >> 6, l = tid & 63;
    int lane15 = l & 15, quad = l >> 4;
    int wave_m = (w >> 1) * 64, wave_n = (w & 1) * 64;

    const unsigned short* Abase = xg + (size_t)pos0 * DIM;
    const unsigned short* Bbase = Wb + (size_t)e * DIM * DIM + (size_t)n0 * DIM;

    // staging source offsets (shorts), invariant across K except +k0.
    // tile side = 512 chunks of 16B; wave w stages chunks [w*128, w*128+128)
    // in 2 issues of 64. chunk c: row=c>>2, dest pos=c&3, src q = pos^((row>>1)&3)
    int srcOff[2];
#pragma unroll
    for (int j = 0; j < 2; j++) {
        int c = w * 128 + j * 64 + l;
        int row = c >> 2, pos = c & 3;
        int q = pos ^ ((row >> 1) & 3);
        srcOff[j] = row * DIM + q * 8;
    }

    // fragment read offsets (shorts), loop-invariant.
    int swz = (quad ^ ((lane15 >> 1) & 3)) * 8;
    int afOff[4], bfOff[4];
#pragma unroll
    for (int mi = 0; mi < 4; mi++)
        afOff[mi] = (wave_m + mi * 16 + lane15) * BK + swz;
#pragma unroll
    for (int ni = 0; ni < 4; ni++)
        bfOff[ni] = 4096 + (wave_n + ni * 16 + lane15) * BK + swz;

    f32x4 acc[4][4];
#pragma unroll
    for (int i = 0; i < 4; i++)
#pragma unroll
        for (int j = 0; j < 4; j++) acc[i][j] = (f32x4){0.f, 0.f, 0.f, 0.f};

#define ISSUE(buf, k0)                                                          \
    do {                                                                        \
        _Pragma("unroll")                                                       \
        for (int j = 0; j < 2; j++) {                                           \
            __builtin_amdgcn_global_load_lds(                                   \
                AS1(Abase + (k0) + srcOff[j]),                                  \
                AS3(&lds[buf][w * 1024 + j * 512]), 16, 0, 0);                  \
            __builtin_amdgcn_global_load_lds(                                   \
                AS1(Bbase + (k0) + srcOff[j]),                                  \
                AS3(&lds[buf][4096 + w * 1024 + j * 512]), 16, 0, 0);           \
        }                                                                       \
    } while (0)

    ISSUE(0, 0);
    ISSUE(1, BK);
    int cur = 0;
    for (int i = 0; i < NITER; ++i) {
        // loads(i) complete; loads(i+1) (4 per wave) stay in flight.
        if (i + 1 < NITER) asm volatile("s_waitcnt vmcnt(4)" ::: "memory");
        else               asm volatile("s_waitcnt vmcnt(0)" ::: "memory");
        __builtin_amdgcn_s_barrier();
        asm volatile("" ::: "memory");
        if (i + 2 < NITER) {
            int nb3 = cur + 2; if (nb3 >= 3) nb3 -= 3;
            ISSUE(nb3, (i + 2) * BK);
        }
        bf16x8 af[4], bf[4];
#pragma unroll
        for (int mi = 0; mi < 4; mi++)
            af[mi] = *(const bf16x8*)(&lds[cur][afOff[mi]]);
#pragma unroll
        for (int ni = 0; ni < 4; ni++)
            bf[ni] = *(const bf16x8*)(&lds[cur][bfOff[ni]]);
#pragma unroll
        for (int mi = 0; mi < 4; mi++)
#pragma unroll
            for (int ni = 0; ni < 4; ni++)
                acc[mi][ni] = __builtin_amdgcn_mfma_f32_16x16x32_bf16(
                    af[mi], bf[ni], acc[mi][ni], 0, 0, 0);
        if (++cur == 3) cur = 0;
    }
#undef ISSUE

    // epilogue: bias + relu + residual(from xg, bf16, contiguous) + scatter
    float bv[4];
#pragma unroll
    for (int ni = 0; ni < 4; ni++)
        bv[ni] = bias[(size_t)e * DIM + n0 + wave_n + ni * 16 + lane15];
#pragma unroll
    for (int mi = 0; mi < 4; mi++) {
#pragma unroll
        for (int r4 = 0; r4 < 4; r4++) {
            int rl = wave_m + mi * 16 + quad * 4 + r4;
            if (rl < valid) {
                int orig = rowmap[pos0 + rl];
                const unsigned short* xrow = xg + (size_t)(pos0 + rl) * DIM + n0;
                float* orow = out + (size_t)orig * DIM + n0;
#pragma unroll
                for (int ni = 0; ni < 4; ni++) {
                    int col = wave_n + ni * 16 + lane15;
                    float xv = __uint_as_float((unsigned)xrow[col] << 16);
                    float v = acc[mi][ni][r4] + bv[ni];
                    v = v > 0.f ? v : 0.f;
                    orow[col] = xv + v;
                }
            }
        }
    }
}

// slow-but-correct fallback if workspace is too small
__global__ void k_naive(const float* __restrict__ x, const int* __restrict__ ids,
                        const float* __restrict__ W, const float* __restrict__ b,
                        float* __restrict__ out) {
    __shared__ float lx[DIM];
    int i = blockIdx.x;
    for (int t = threadIdx.x; t < DIM; t += blockDim.x) lx[t] = x[(size_t)i * DIM + t];
    __syncthreads();
    int e = ids[i];
    const float* We = W + (size_t)e * DIM * DIM;
    for (int n = threadIdx.x; n < DIM; n += blockDim.x) {
        const float* wr = We + (size_t)n * DIM;
        float acc = 0.f;
        for (int k = 0; k < DIM; k += 4) {
            float4 w4 = *(const float4*)(wr + k);
            acc += lx[k] * w4.x + lx[k + 1] * w4.y + lx[k + 2] * w4.z + lx[k + 3] * w4.w;
        }
        float v = acc + b[(size_t)e * DIM + n];
        v = v > 0.f ? v : 0.f;
        out[(size_t)i * DIM + n] = lx[n] + v;
    }
}

extern "C" void kernel_launch(void* const* d_in, const int* in_sizes, int n_in,
                              void* d_out, int out_size, void* d_ws, size_t ws_size,
                              hipStream_t stream) {
    const float* x   = (const float*)d_in[0];
    const int*   ids = (const int*)d_in[1];
    const float* W   = (const float*)d_in[2];
    const float* b   = (const float*)d_in[3];
    float* out = (float*)d_out;

    if (ws_size < WS_NEED) {
        k_naive<<<BATCH, 256, 0, stream>>>(x, ids, W, b, out);
        return;
    }

    char* wsb = (char*)d_ws;
    int*  wsi = (int*)wsb;
    unsigned short* xg = (unsigned short*)(wsb + XG_BYTE_OFF);
    unsigned short* Wb = (unsigned short*)(wsb + WB_BYTE_OFF);
    int* rowmap = wsi + 512;

    k_plan<<<1, 256, 0, stream>>>(ids, wsi);
    k_prep<<<BATCH + NPAD + NCVT, 256, 0, stream>>>(x, ids, wsi, xg, rowmap,
                                                    (const float4*)W, (uint4*)Wb);
    k_gemm<<<NBLK * MAX_TILES, 256, 0, stream>>>(xg, Wb, b, wsi, rowmap, out);
}

// Round 2
// 403.045 us; speedup vs baseline: 1.1618x; 1.1618x over previous
//
#include <hip/hip_runtime.h>
#include <hip/hip_bf16.h>
#include <stdint.h>

#define BATCH 8192
#define DIM   2048
#define NEXP  8
#define BM    128
#define BN    128
#define BK    32
#define NITER (DIM / BK)   // 64
#define MAX_TILES 72
#define NBLK  (DIM / BN)   // 16
#define NROWS 9216         // BATCH + max padding (8*128)
#define NCVTB 4096         // W cvt blocks: 8*2048*2048 bf16 / 16B / 256thr / 4chunks

typedef __bf16 bf16x8 __attribute__((ext_vector_type(8)));
typedef float  f32x4  __attribute__((ext_vector_type(4)));

// ---- workspace layout ----
// counts@0(8) seg@32(8) ntiles@48 paddedTotal@49 tileExp@64(96) tilePos0@160(96)
// tileVal@256(96) rowmap@512(9216 ints)
// xg (bf16) @ byte 40960 ; Wb (bf16) @ byte 37,789,696
#define XG_BYTE_OFF 40960ull
#define WB_BYTE_OFF 37789696ull
#define WS_NEED     104898560ull

#define AS1(p) ((const __attribute__((address_space(1))) void*)(p))
#define AS3(p) ((__attribute__((address_space(3))) void*)(p))

__device__ __forceinline__ unsigned f2bf2(float lo, float hi) {
    unsigned ul = __float_as_uint(lo), uh = __float_as_uint(hi);
    ul = (ul + 0x7FFFu + ((ul >> 16) & 1u)) >> 16;   // RNE
    uh = (uh + 0x7FFFu + ((uh >> 16) & 1u)) >> 16;
    return (uh << 16) | ul;
}

// single block: histogram -> exclusive scan -> deterministic rank assignment.
// NO atomics anywhere. rowmap[p] = original row for compacted position p,
// -1 for padding rows.
__global__ void k_plan(const int* __restrict__ ids, int* __restrict__ ws,
                       int* __restrict__ rowmap) {
    __shared__ int sc[256 * NEXP];   // per-thread per-expert counts -> prefixes
    __shared__ int seg[NEXP];
    __shared__ int tot[NEXP];
    int t = threadIdx.x;
#pragma unroll
    for (int e = 0; e < NEXP; e++) sc[t * NEXP + e] = 0;
    int base = t * 32;               // each thread owns 32 consecutive rows
    for (int i = 0; i < 32; i++) sc[t * NEXP + ids[base + i]]++;
    __syncthreads();
    if (t < NEXP) {                  // exclusive scan across threads, expert t
        int run = 0;
        for (int j = 0; j < 256; j++) {
            int v = sc[j * NEXP + t];
            sc[j * NEXP + t] = run;
            run += v;
        }
        tot[t] = run;
    }
    __syncthreads();
    if (t == 0) {
        int pos = 0, mt = 0;
        for (int e = 0; e < NEXP; e++) {
            int c = tot[e];
            seg[e]     = pos;
            ws[e]      = c;
            ws[32 + e] = pos;
            int ntl = (c + BM - 1) / BM;
            for (int tt = 0; tt < ntl; tt++) {
                ws[64  + mt] = e;
                ws[160 + mt] = pos + tt * BM;
                int v = c - tt * BM;
                ws[256 + mt] = v < BM ? v : BM;
                mt++;
            }
            pos += ntl * BM;
        }
        ws[48] = mt;
        ws[49] = pos;
    }
    __syncthreads();
    for (int i = t; i < NROWS; i += 256) rowmap[i] = -1;
    __syncthreads();                 // init stores drained before overwrite
    for (int i = 0; i < 32; i++) {
        int e = ids[base + i];
        int p = seg[e] + sc[t * NEXP + e]++;
        rowmap[p] = base + i;
    }
}

// merged preprocessing, fully parallel, zero atomics / zero intra-block sync:
//   blocks [0, NROWS)         : dest row p: rowmap[p]>=0 -> gather+convert
//                               x[rowmap[p]] into xg[p]; else zero-fill
//   blocks [NROWS, +NCVTB)    : W fp32 -> bf16, 4 coalesced chunks/thread
__global__ void k_prep(const float* __restrict__ x,
                       const int* __restrict__ rowmap,
                       unsigned short* __restrict__ xg,
                       const float4* __restrict__ W, uint4* __restrict__ Wb) {
    int b = blockIdx.x;
    int t = threadIdx.x;
    if (b >= NROWS) {
        // ---- W conversion: 32B in / 16B out per thread per chunk, 4 chunks
        size_t base = (size_t)(b - NROWS) * 1024;   // uint4 index
#pragma unroll
        for (int j = 0; j < 4; j++) {
            size_t o = base + (size_t)j * 256 + t;
            float4 a = W[o * 2], c = W[o * 2 + 1];
            uint4 v;
            v.x = f2bf2(a.x, a.y);  v.y = f2bf2(a.z, a.w);
            v.z = f2bf2(c.x, c.y);  v.w = f2bf2(c.z, c.w);
            Wb[o] = v;
        }
        return;
    }
    int orig = rowmap[b];            // uniform -> scalar load
    uint4* o = (uint4*)(xg + (size_t)b * DIM);
    if (orig < 0) {
        o[t] = make_uint4(0, 0, 0, 0);
        return;
    }
    const float4* xr = (const float4*)(x + (size_t)orig * DIM);
    float4 a = xr[t * 2], b4 = xr[t * 2 + 1];
    uint4 v;
    v.x = f2bf2(a.x, a.y);   v.y = f2bf2(a.z, a.w);
    v.z = f2bf2(b4.x, b4.y); v.w = f2bf2(b4.z, b4.w);
    o[t] = v;
}

// grouped GEMM: 128x128 tile, 4 waves (2x2 of 64x64), BK=32,
// DOUBLE-BUFFERED LDS (proven round-0 schedule: single barrier per iter,
// prefetch i+1 during compute i; __syncthreads drains vmcnt(0)).
// Swizzle: 16B chunk at LDS position p of row r holds logical chunk
// p ^ ((r>>1)&3) -> 2-way (free) bank aliasing on ds_read_b128 phases,
// applied on the STAGING SOURCE address (dest stays wave-uniform contiguous).
// Grid mapping: all 16 n-blocks of an m-tile land on one XCD (A-panel L2
// locality); m-tiles round-robin across XCDs (balanced for any tile count).
__launch_bounds__(256)
__global__ void k_gemm(const unsigned short* __restrict__ xg,
                       const unsigned short* __restrict__ Wb,
                       const float* __restrict__ bias,
                       const int* __restrict__ ws, const int* __restrict__ rowmap,
                       float* __restrict__ out) {
    int bid = blockIdx.x;                 // 0..1151
    int g = bid >> 3, r = bid & 7;        // XCD = bid % 8
    int nb = g & 15;                      // n-block within m-tile
    int mt = ((g >> 4) << 3) + r;         // m-tile, round-robin across XCDs
    if (mt >= ws[48]) return;
    int e     = ws[64  + mt];
    int pos0  = ws[160 + mt];
    int valid = ws[256 + mt];
    int n0 = nb * BN;

    __shared__ unsigned short lds[2][8192];  // [buf][0..4095]=A, [4096..8191]=B; 32 KB

    int tid = threadIdx.x;
    int w = tid >> 6, l = tid & 63;
    int lane15 = l & 15, quad = l >> 4;
    int wave_m = (w >> 1) * 64, wave_n = (w & 1) * 64;

    const unsigned short* Abase = xg + (size_t)pos0 * DIM;
    const unsigned short* Bbase = Wb + (size_t)e * DIM * DIM + (size_t)n0 * DIM;

    // staging source offsets (shorts), invariant across K except +k0.
    // tile side = 512 chunks of 16B; wave w stages chunks [w*128, w*128+128)
    // in 2 issues of 64. chunk c: row=c>>2, dest pos=c&3, src q = pos^((row>>1)&3)
    int srcOff[2];
#pragma unroll
    for (int j = 0; j < 2; j++) {
        int c = w * 128 + j * 64 + l;
        int row = c >> 2, pos = c & 3;
        int q = pos ^ ((row >> 1) & 3);
        srcOff[j] = row * DIM + q * 8;
    }

    // fragment read offsets (shorts), loop-invariant.
    int swz = (quad ^ ((lane15 >> 1) & 3)) * 8;
    int afOff[4], bfOff[4];
#pragma unroll
    for (int mi = 0; mi < 4; mi++)
        afOff[mi] = (wave_m + mi * 16 + lane15) * BK + swz;
#pragma unroll
    for (int ni = 0; ni < 4; ni++)
        bfOff[ni] = 4096 + (wave_n + ni * 16 + lane15) * BK + swz;

    f32x4 acc[4][4];
#pragma unroll
    for (int i = 0; i < 4; i++)
#pragma unroll
        for (int j = 0; j < 4; j++) acc[i][j] = (f32x4){0.f, 0.f, 0.f, 0.f};

#define ISSUE(buf, k0)                                                          \
    do {                                                                        \
        _Pragma("unroll")                                                       \
        for (int j = 0; j < 2; j++) {                                           \
            __builtin_amdgcn_global_load_lds(                                   \
                AS1(Abase + (k0) + srcOff[j]),                                  \
                AS3(&lds[buf][w * 1024 + j * 512]), 16, 0, 0);                  \
            __builtin_amdgcn_global_load_lds(                                   \
                AS1(Bbase + (k0) + srcOff[j]),                                  \
                AS3(&lds[buf][4096 + w * 1024 + j * 512]), 16, 0, 0);           \
        }                                                                       \
    } while (0)

    ISSUE(0, 0);
    int cur = 0;
    for (int i = 0; i < NITER; ++i) {
        __syncthreads();   // drains vmcnt(0): loads(i) complete (in flight
                           // during compute(i-1)); all compute(i-1) done.
        if (i + 1 < NITER) {
            int k0n = (i + 1) * BK;
            ISSUE(cur ^ 1, k0n);
        }
        bf16x8 af[4], bf[4];
#pragma unroll
        for (int mi = 0; mi < 4; mi++)
            af[mi] = *(const bf16x8*)(&lds[cur][afOff[mi]]);
#pragma unroll
        for (int ni = 0; ni < 4; ni++)
            bf[ni] = *(const bf16x8*)(&lds[cur][bfOff[ni]]);
#pragma unroll
        for (int mi = 0; mi < 4; mi++)
#pragma unroll
            for (int ni = 0; ni < 4; ni++)
                acc[mi][ni] = __builtin_amdgcn_mfma_f32_16x16x32_bf16(
                    af[mi], bf[ni], acc[mi][ni], 0, 0, 0);
        cur ^= 1;
    }
#undef ISSUE

    // epilogue: bias + relu + residual(from xg, bf16, contiguous) + scatter
    float bv[4];
#pragma unroll
    for (int ni = 0; ni < 4; ni++)
        bv[ni] = bias[(size_t)e * DIM + n0 + wave_n + ni * 16 + lane15];
#pragma unroll
    for (int mi = 0; mi < 4; mi++) {
#pragma unroll
        for (int r4 = 0; r4 < 4; r4++) {
            int rl = wave_m + mi * 16 + quad * 4 + r4;
            if (rl < valid) {
                int orig = rowmap[pos0 + rl];
                const unsigned short* xrow = xg + (size_t)(pos0 + rl) * DIM + n0;
                float* orow = out + (size_t)orig * DIM + n0;
#pragma unroll
                for (int ni = 0; ni < 4; ni++) {
                    int col = wave_n + ni * 16 + lane15;
                    float xv = __uint_as_float((unsigned)xrow[col] << 16);
                    float v = acc[mi][ni][r4] + bv[ni];
                    v = v > 0.f ? v : 0.f;
                    orow[col] = xv + v;
                }
            }
        }
    }
}

// slow-but-correct fallback if workspace is too small
__global__ void k_naive(const float* __restrict__ x, const int* __restrict__ ids,
                        const float* __restrict__ W, const float* __restrict__ b,
                        float* __restrict__ out) {
    __shared__ float lx[DIM];
    int i = blockIdx.x;
    for (int t = threadIdx.x; t < DIM; t += blockDim.x) lx[t] = x[(size_t)i * DIM + t];
    __syncthreads();
    int e = ids[i];
    const float* We = W + (size_t)e * DIM * DIM;
    for (int n = threadIdx.x; n < DIM; n += blockDim.x) {
        const float* wr = We + (size_t)n * DIM;
        float acc = 0.f;
        for (int k = 0; k < DIM; k += 4) {
            float4 w4 = *(const float4*)(wr + k);
            acc += lx[k] * w4.x + lx[k + 1] * w4.y + lx[k + 2] * w4.z + lx[k + 3] * w4.w;
        }
        float v = acc + b[(size_t)e * DIM + n];
        v = v > 0.f ? v : 0.f;
        out[(size_t)i * DIM + n] = lx[n] + v;
    }
}

extern "C" void kernel_launch(void* const* d_in, const int* in_sizes, int n_in,
                              void* d_out, int out_size, void* d_ws, size_t ws_size,
                              hipStream_t stream) {
    const float* x   = (const float*)d_in[0];
    const int*   ids = (const int*)d_in[1];
    const float* W   = (const float*)d_in[2];
    const float* b   = (const float*)d_in[3];
    float* out = (float*)d_out;

    if (ws_size < WS_NEED) {
        k_naive<<<BATCH, 256, 0, stream>>>(x, ids, W, b, out);
        return;
    }

    char* wsb = (char*)d_ws;
    int*  wsi = (int*)wsb;
    unsigned short* xg = (unsigned short*)(wsb + XG_BYTE_OFF);
    unsigned short* Wb = (unsigned short*)(wsb + WB_BYTE_OFF);
    int* rowmap = wsi + 512;

    k_plan<<<1, 256, 0, stream>>>(ids, wsi, rowmap);
    k_prep<<<NROWS + NCVTB, 256, 0, stream>>>(x, rowmap, xg,
                                              (const float4*)W, (uint4*)Wb);
    k_gemm<<<NBLK * MAX_TILES, 256, 0, stream>>>(xg, Wb, b, wsi, rowmap, out);
}